// Round 12
// baseline (278.878 us; speedup 1.0000x reference)
//
#include <hip/hip_runtime.h>

namespace {
constexpr int B = 1024, Q = 128, P = 32, N = 128, D = 64, K = 160;

// ---------------- mean distance over cdist(x, y_pos) ----------------
__global__ __launch_bounds__(256) void k_meandist(
    const float* __restrict__ x, const float* __restrict__ y_pos,
    double* __restrict__ ws) {
  __shared__ float Yp[P][D];
  __shared__ float ysq[P];
  __shared__ float red[4];
  const int b = blockIdx.x, tid = threadIdx.x;
  const float* yb = y_pos + (size_t)b * P * D;
  for (int i = tid; i < P * D / 4; i += 256)
    reinterpret_cast<float4*>(&Yp[0][0])[i] = reinterpret_cast<const float4*>(yb)[i];
  __syncthreads();
  if (tid < P) {
    float s = 0.f;
    for (int d = 0; d < D; ++d) { float v = Yp[tid][d]; s = fmaf(v, v, s); }
    ysq[tid] = s;
  }
  __syncthreads();
  const int q = tid >> 1, ph = tid & 1;
  const float* xq = x + ((size_t)b * Q + q) * D;
  float acc[16];
#pragma unroll
  for (int j = 0; j < 16; ++j) acc[j] = 0.f;
  float xsq = 0.f;
#pragma unroll 1
  for (int d4 = 0; d4 < 16; ++d4) {
    float4 xv = reinterpret_cast<const float4*>(xq)[d4];
    xsq = fmaf(xv.x, xv.x, fmaf(xv.y, xv.y, fmaf(xv.z, xv.z, fmaf(xv.w, xv.w, xsq))));
#pragma unroll
    for (int j = 0; j < 16; ++j) {
      float4 yv = reinterpret_cast<const float4*>(&Yp[ph * 16 + j][0])[d4];
      acc[j] = fmaf(xv.x, yv.x, fmaf(xv.y, yv.y, fmaf(xv.z, yv.z, fmaf(xv.w, yv.w, acc[j]))));
    }
  }
  float dsum = 0.f;
#pragma unroll
  for (int j = 0; j < 16; ++j) {
    float d2 = xsq + ysq[ph * 16 + j] - 2.f * acc[j];
    dsum += sqrtf(fmaxf(d2, 0.f));
  }
#pragma unroll
  for (int m = 1; m < 64; m <<= 1) dsum += __shfl_xor(dsum, m);
  if ((tid & 63) == 0) red[tid >> 6] = dsum;
  __syncthreads();
  if (tid == 0)
    atomicAdd(ws, (double)(red[0] + red[1] + red[2] + red[3]));
}

// ---------------- fused drift kernel: 1024 thr, <=64-VGPR/<=70KB regime ----
// Occupancy facts from R5-R11: 512-thr blocks NEVER co-reside (22.7% always);
// one 1024-thr block gives 16 waves/CU (45.8%, R11). Two 1024-thr blocks
// need LDS <= ~80KB AND VGPR <= 64 (512-reg/SIMD pool / 8 waves).
// Design: zz[4][5]=20 + dr[4][4]=16 (2-way k-split GEMM), C as a
// single-buffered 40-k slab (21KB) aliased with X staging -> LDS 69.3KB,
// worst-phase live ~55. waves_per_eu(2,8): budget 128, max 8 waves/EU.
__global__
__attribute__((amdgpu_flat_work_group_size(1024, 1024)))
__attribute__((amdgpu_waves_per_eu(2, 8)))
void k_drift4(
    const float* __restrict__ x, const float* __restrict__ y_pos,
    const float* __restrict__ y_neg, double* __restrict__ ws) {
  // LDS map (floats), total 17328 f = 69312 B:
  //  [0,10240)      Y4 [160][16] f4 row-rotated by k (reused as merge buf)
  //  [10240,15520)  union: X4c [128][8] f4 (4096 f) / C slab [40][33] f4 (5280 f)
  //  [15520,15904)  rss [3][128]
  //  [15904,16384)  css [3][160] -> rsqrt in place
  //  [16384,16768)  uss [3][128] -> /rs in place
  //  [16768,17152)  vss [3][128] -> /rs in place
  //  [17152,17312)  ysq [160]
  //  [17312,17328)  redd (8 doubles)
  __shared__ __align__(16) float SM[17328];
  float4* Y4  = (float4*)SM;
  float4* X4c = (float4*)(SM + 10240);
  float4* C4s = (float4*)(SM + 10240);
  float* rss = SM + 15520;
  float* css = SM + 15904;
  float* uss = SM + 16384;
  float* vss = SM + 16768;
  float* ysq = SM + 17152;
  double* redd = (double*)(SM + 17312);

  const int b = blockIdx.x, tid = threadIdx.x;
  const float4* yn4 = (const float4*)(y_neg + (size_t)b * N * D);
  const float4* yp4 = (const float4*)(y_pos + (size_t)b * P * D);
  const float4* xg  = (const float4*)(x + (size_t)b * Q * D);

  // ---- stage Y (rotated) + zero sums ----
  for (int idx = tid; idx < K * 16; idx += 1024) {
    int k = idx >> 4, d4 = idx & 15;
    float4 v = (k < N) ? yn4[k * 16 + d4] : yp4[(k - N) * 16 + d4];
    Y4[k * 16 + ((d4 + k) & 15)] = v;
  }
  if (tid < 384) { rss[tid] = 0.f; uss[tid] = 0.f; vss[tid] = 0.f; }

  // producer mapping: qg = tid&31 -> q in [4qg,4qg+4); kt = tid>>5 (0..31),
  // k = kt + 32j (j=0..4; j==4 <=> pos)
  const int qg = tid & 31, kt = tid >> 5;
  const int qb = qg * 4;

  float zz[4][5], xs4[4];
#pragma unroll
  for (int i = 0; i < 4; ++i) {
    xs4[i] = 0.f;
#pragma unroll
    for (int j = 0; j < 5; ++j) zz[i][j] = 0.f;
  }

  // ---- dist phase: X staged in 2 chunks of 8 f4-cols (aliased region) ----
#pragma unroll 1
  for (int ch = 0; ch < 2; ++ch) {
    __syncthreads();                  // Y staged (ch0) / prev chunk consumed
    {
      int q = tid >> 3, c = tid & 7;  // one f4 store per thread
      X4c[q * 8 + ((c + (q >> 2)) & 7)] = xg[q * 16 + ch * 8 + c];
    }
    __syncthreads();
    if (ch == 0 && tid < K) {         // ysq once, after Y visible
      float s = 0.f;
#pragma unroll
      for (int c = 0; c < 16; ++c) {
        float4 v = Y4[tid * 16 + ((c + tid) & 15)];
        s = fmaf(v.x, v.x, fmaf(v.y, v.y, fmaf(v.z, v.z, fmaf(v.w, v.w, s))));
      }
      ysq[tid] = s;
    }
#pragma unroll 2
    for (int d4 = 0; d4 < 8; ++d4) {
      const int gd4 = ch * 8 + d4;
      const int rx = (d4 + qg) & 7;
      float4 xv[4];
#pragma unroll
      for (int i = 0; i < 4; ++i) xv[i] = X4c[(qb + i) * 8 + rx];
#pragma unroll
      for (int i = 0; i < 4; ++i)
        xs4[i] = fmaf(xv[i].x, xv[i].x, fmaf(xv[i].y, xv[i].y,
                 fmaf(xv[i].z, xv[i].z, fmaf(xv[i].w, xv[i].w, xs4[i]))));
#pragma unroll
      for (int j = 0; j < 5; ++j) {
        const int k_ = kt + 32 * j;
        float4 yv = Y4[k_ * 16 + ((gd4 + k_) & 15)];
#pragma unroll
        for (int i = 0; i < 4; ++i)
          zz[i][j] = fmaf(xv[i].x, yv.x, fmaf(xv[i].y, yv.y,
                     fmaf(xv[i].z, yv.z, fmaf(xv[i].w, yv.w, zz[i][j]))));
      }
    }
  }

  const float meand = (float)(ws[0] * (1.0 / ((double)B * Q * P)));
  const float invt2 = 1.0f / fmaxf(meand, 1e-6f);
#pragma unroll
  for (int i = 0; i < 4; ++i)
#pragma unroll
    for (int j = 0; j < 5; ++j) {
      const int k_ = kt + 32 * j;
      float d2 = xs4[i] + ysq[k_] - 2.f * zz[i][j];
      zz[i][j] = __expf(-sqrtf(fmaxf(d2, 0.f)) * invt2);
    }

  // ---- pass 1: row sums (rss) / col sums (css) per temp ----
  // wave: lanes 0-31 kt=2w, lanes 32-63 kt=2w+1; qg = lane&31.
#pragma unroll
  for (int t = 0; t < 3; ++t) {
    float ers[4] = {0.f, 0.f, 0.f, 0.f};
    float ecs[5] = {0.f, 0.f, 0.f, 0.f, 0.f};
#pragma unroll
    for (int i = 0; i < 4; ++i)
#pragma unroll
      for (int j = 0; j < 5; ++j) {
        float z = zz[i][j], f;
        if (t == 2) f = z;
        else if (t == 1) f = z * z;
        else { float z2 = z * z, z4 = z2 * z2; f = z4 * z4 * z2; }
        ers[i] += f; ecs[j] += f;
      }
#pragma unroll
    for (int j = 0; j < 5; ++j) {     // col sum over 32 qg (half-wave)
      float v = ecs[j];
      v += __shfl_xor(v, 1); v += __shfl_xor(v, 2);
      v += __shfl_xor(v, 4); v += __shfl_xor(v, 8); v += __shfl_xor(v, 16);
      if (qg == 0) css[t * 160 + kt + 32 * j] = v;
    }
#pragma unroll
    for (int i = 0; i < 4; ++i) {     // rows: pair kt halves, atomic
      float v = ers[i];
      v += __shfl_xor(v, 32);
      if ((tid & 63) < 32) atomicAdd(&rss[t * 128 + qb + i], v);
    }
  }
  __syncthreads();
  if (tid < 480) css[tid] = rsqrtf(css[tid]);
  __syncthreads();

  // ---- pass 2: sum_pos (uss) / sum_neg (vss) of e*ics per (temp, q) ----
#pragma unroll
  for (int t = 0; t < 3; ++t) {
    float icr[5];
#pragma unroll
    for (int j = 0; j < 5; ++j) icr[j] = css[t * 160 + kt + 32 * j];
    float uu[4] = {0.f, 0.f, 0.f, 0.f};
    float vv[4] = {0.f, 0.f, 0.f, 0.f};
#pragma unroll
    for (int i = 0; i < 4; ++i)
#pragma unroll
      for (int j = 0; j < 5; ++j) {
        float z = zz[i][j], f;
        if (t == 2) f = z;
        else if (t == 1) f = z * z;
        else { float z2 = z * z, z4 = z2 * z2; f = z4 * z4 * z2; }
        float a = f * icr[j];
        if (j == 4) uu[i] += a; else vv[i] += a;
      }
#pragma unroll
    for (int i = 0; i < 4; ++i) {
      float u = uu[i]; u += __shfl_xor(u, 32);
      float v = vv[i]; v += __shfl_xor(v, 32);
      if ((tid & 63) < 32) {
        atomicAdd(&uss[t * 128 + qb + i], u);
        atomicAdd(&vss[t * 128 + qb + i], v);
      }
    }
  }
  __syncthreads();
  if (tid < 384) {
    float inv = 1.0f / rss[tid];
    uss[tid] *= inv;
    vss[tid] *= inv;
  }

  // ---- 4 slabs: produce combined coefficients (40 k), consume as GEMM ----
  // consumer: kc = tid>>9 (2-way k-split), qc = (tid>>4)&31, dcc = tid&15.
  const int kc = tid >> 9, qc = (tid >> 4) & 31, dcc = tid & 15;
  float dr[4][4];
#pragma unroll
  for (int i = 0; i < 4; ++i)
#pragma unroll
    for (int n = 0; n < 4; ++n) dr[i][n] = 0.f;

#pragma unroll 1
  for (int s = 0; s < 4; ++s) {
    __syncthreads();    // slab buffer free (s=0: also covers uss/vss scaling)
#pragma unroll
    for (int j = 0; j < 5; ++j) {
      const int klocal = kt + 32 * j - 40 * s;
      if (klocal >= 0 && klocal < 40) {
        const int k_ = kt + 32 * j;
        const bool pos = (j == 4);
        const float ic0 = css[k_], ic1 = css[160 + k_], ic2 = css[320 + k_];
        float c0a[4];
#pragma unroll
        for (int i = 0; i < 4; ++i) {
          const int q2 = qb + i;
          float a0 = pos ? vss[q2]       : uss[q2];
          float a1 = pos ? vss[128 + q2] : uss[128 + q2];
          float a2 = pos ? vss[256 + q2] : uss[256 + q2];
          float z = zz[i][j], z2 = z * z, z4 = z2 * z2, z10 = z4 * z4 * z2;
          float c = fmaf(z, ic2 * a2, fmaf(z2, ic1 * a1, z10 * (ic0 * a0)));
          c0a[i] = pos ? c : -c;
        }
        C4s[klocal * 33 + qg] = make_float4(c0a[0], c0a[1], c0a[2], c0a[3]);
      }
    }
    __syncthreads();
#pragma unroll 4
    for (int kl = 0; kl < 20; ++kl) {
      const int klocal = kc * 20 + kl;
      const int k_ = 40 * s + klocal;
      float4 ca = C4s[klocal * 33 + qc];
      float4 y0 = Y4[k_ * 16 + ((dcc + k_) & 15)];
      dr[0][0] = fmaf(ca.x, y0.x, dr[0][0]);
      dr[0][1] = fmaf(ca.x, y0.y, dr[0][1]);
      dr[0][2] = fmaf(ca.x, y0.z, dr[0][2]);
      dr[0][3] = fmaf(ca.x, y0.w, dr[0][3]);
      dr[1][0] = fmaf(ca.y, y0.x, dr[1][0]);
      dr[1][1] = fmaf(ca.y, y0.y, dr[1][1]);
      dr[1][2] = fmaf(ca.y, y0.z, dr[1][2]);
      dr[1][3] = fmaf(ca.y, y0.w, dr[1][3]);
      dr[2][0] = fmaf(ca.z, y0.x, dr[2][0]);
      dr[2][1] = fmaf(ca.z, y0.y, dr[2][1]);
      dr[2][2] = fmaf(ca.z, y0.z, dr[2][2]);
      dr[2][3] = fmaf(ca.z, y0.w, dr[2][3]);
      dr[3][0] = fmaf(ca.w, y0.x, dr[3][0]);
      dr[3][1] = fmaf(ca.w, y0.y, dr[3][1]);
      dr[3][2] = fmaf(ca.w, y0.z, dr[3][2]);
      dr[3][3] = fmaf(ca.w, y0.w, dr[3][3]);
    }
  }
  __syncthreads();   // all GEMM reads of Y done -> Y reusable as merge buf

  // ---- merge the 2 kc partials (via freed Y region) + loss reduction ----
  float4* FB = Y4;
  if (kc == 1) {
#pragma unroll
    for (int i = 0; i < 4; ++i) {
      const int q = qc * 4 + i;
      FB[q * 16 + ((dcc + q) & 15)] =
          make_float4(dr[i][0], dr[i][1], dr[i][2], dr[i][3]);
    }
  }
  __syncthreads();
  if (kc == 0) {
    float tot = 0.f;
#pragma unroll
    for (int i = 0; i < 4; ++i) {
      const int q = qc * 4 + i;
      float4 v = FB[q * 16 + ((dcc + q) & 15)];
      float a0 = dr[i][0] + v.x;
      float a1 = dr[i][1] + v.y;
      float a2 = dr[i][2] + v.z;
      float a3 = dr[i][3] + v.w;
      tot = fmaf(a0, a0, tot); tot = fmaf(a1, a1, tot);
      tot = fmaf(a2, a2, tot); tot = fmaf(a3, a3, tot);
    }
#pragma unroll
    for (int m = 1; m < 64; m <<= 1) tot += __shfl_xor(tot, m);
    if ((tid & 63) == 0) redd[tid >> 6] = (double)tot;   // waves 0..7
  }
  __syncthreads();
  if (tid == 0) {
    double sT = 0.0;
#pragma unroll
    for (int w = 0; w < 8; ++w) sT += redd[w];
    atomicAdd(ws + 1, sT);
  }
}

__global__ void k_final(const double* __restrict__ ws, float* __restrict__ out) {
  out[0] = (float)(ws[1] / ((double)B * Q * D));
}

}  // namespace

extern "C" void kernel_launch(void* const* d_in, const int* in_sizes, int n_in,
                              void* d_out, int out_size, void* d_ws, size_t ws_size,
                              hipStream_t stream) {
  const float* x = (const float*)d_in[0];
  const float* y_pos = (const float*)d_in[1];
  const float* y_neg = (const float*)d_in[2];
  float* out = (float*)d_out;
  double* ws = (double*)d_ws;

  hipMemsetAsync(d_ws, 0, 2 * sizeof(double), stream);
  k_meandist<<<B, 256, 0, stream>>>(x, y_pos, ws);
  k_drift4<<<B, 1024, 0, stream>>>(x, y_pos, y_neg, ws);
  k_final<<<1, 1, 0, stream>>>(ws, out);
}